// Round 3
// baseline (8476.402 us; speedup 1.0000x reference)
//
#include <hip/hip_runtime.h>

#define BB   128   // batch
#define TT   1024  // time steps
#define INP  256   // input dim
#define HH   512   // hidden dim
#define OUTD 256   // output dim
#define GB   16    // batches per group
#define NG   8     // groups (one per XCD via blockIdx%8)
#define NBLK 128   // 8 groups x (8 L0-blocks + 8 L1-blocks)

typedef float  f32x4  __attribute__((ext_vector_type(4)));
typedef short  short8 __attribute__((ext_vector_type(8)));

__device__ __forceinline__ unsigned short bf16_rne(float f) {
  union { float f; unsigned u; } v; v.f = f;
  unsigned r = v.u + 0x7fffu + ((v.u >> 16) & 1u);
  return (unsigned short)(r >> 16);
}

__device__ __forceinline__ short8 pack8(f32x4 a, f32x4 b) {
  union { unsigned short s[8]; short8 v; } u;
  u.s[0] = bf16_rne(a[0]); u.s[1] = bf16_rne(a[1]);
  u.s[2] = bf16_rne(a[2]); u.s[3] = bf16_rne(a[3]);
  u.s[4] = bf16_rne(b[0]); u.s[5] = bf16_rne(b[1]);
  u.s[6] = bf16_rne(b[2]); u.s[7] = bf16_rne(b[3]);
  return u.v;
}

// load 8 contiguous fp32, convert to 8 bf16 (cached path, for weights/init)
__device__ __forceinline__ short8 load_cvt8(const float* p) {
  const f32x4* q = (const f32x4*)p;
  return pack8(q[0], q[1]);
}

__device__ __forceinline__ f32x4 ntload4(const float* p) {
  return __builtin_nontemporal_load((const f32x4*)p);
}

// Monotonic-counter group barrier (16 blocks). Relaxed polling + one acquire
// at exit (L1 invalidate once). __syncthreads at entry drains each wave's
// vmem (compiler emits s_waitcnt vmcnt(0) before s_barrier), so all block
// stores are L2-visible before thread 0's release-add.
__device__ __forceinline__ void gbar(unsigned* cnt, unsigned target) {
  __syncthreads();
  if (threadIdx.x == 0) {
    __hip_atomic_fetch_add(cnt, 1u, __ATOMIC_RELEASE, __HIP_MEMORY_SCOPE_AGENT);
    while (__hip_atomic_load(cnt, __ATOMIC_RELAXED, __HIP_MEMORY_SCOPE_AGENT) < target)
      __builtin_amdgcn_s_sleep(1);
    (void)__hip_atomic_load(cnt, __ATOMIC_ACQUIRE, __HIP_MEMORY_SCOPE_AGENT);
  }
  __syncthreads();
}

// h-state fragment buffers: [buf(2)][group(8)] x [kb(16)][lane(64)][e(8)] bf16.
// Value (b_local, j): kb = j>>5, lane' = ((j>>3)&3)*16 + b_local, e = j&7.
__device__ __forceinline__ unsigned short* hsl(unsigned short* base, int buf, int g) {
  return base + ((size_t)(buf * NG + g)) * (16 * 64 * 8);
}

__global__ void __launch_bounds__(256, 1) rnn_mfma(
    const float* __restrict__ x,       // [B][T][IN]
    const float* __restrict__ h0init,  // [2][B][H]
    const float* __restrict__ w_ih0,   // [H][IN]
    const float* __restrict__ w_hh0,   // [H][H]
    const float* __restrict__ b_ih0,   // [H]
    const float* __restrict__ b_hh0,   // [H]
    const float* __restrict__ w_ih1,   // [H][H]
    const float* __restrict__ w_hh1,   // [H][H]
    const float* __restrict__ b_ih1,   // [H]
    const float* __restrict__ b_hh1,   // [H]
    const float* __restrict__ fc_w,    // [OUT][H]
    const float* __restrict__ fc_b,    // [OUT]
    float* __restrict__ out,           // [B][OUT]
    unsigned* __restrict__ bar,        // NG counters, 64B apart
    unsigned short* __restrict__ h0f,  // h0 frag dbuf
    unsigned short* __restrict__ h1f)  // h1 frag dbuf
{
  const int g    = blockIdx.x & 7;       // group -> XCD locality
  const int role = blockIdx.x >> 3;      // 0..7: layer0 j-tiles, 8..15: layer1
  const bool isL0 = role < 8;
  const int tid  = threadIdx.x;
  const int wv   = tid >> 6;
  const int lane = tid & 63;
  const int ln   = lane & 15;            // A-row (batch) / B-col (j) / D-col
  const int q    = lane >> 4;            // quad
  const int jrel = wv * 16 + ln;         // j within block's 64-wide slice
  const int j    = (role & 7) * 64 + jrel;
  const int bg   = g * GB;
  unsigned* cnt  = bar + g * 16;
  unsigned phase = 0;

  __shared__ unsigned short hstage[1024];  // 2KB LDS transpose stage

  // ---- init: h0init -> frag buffers, buf 1 (read at first use).
  for (int c = tid; c < 2048; c += 256) {
    int a  = c >> 10;            // 0 -> h0, 1 -> h1
    int bl = (c >> 6) & 15;
    int j8 = (c & 63) * 8;
    short8 v = load_cvt8(h0init + ((size_t)a * BB + (bg + bl)) * HH + j8);
    unsigned short* dst = hsl(a ? h1f : h0f, 1, g)
        + ((size_t)((j8 >> 5) * 64 + ((j8 >> 3) & 3) * 16 + bl)) * 8;
    *(short8*)dst = v;
  }

  // ---- weight B-fragments -> registers (once). Lane: row j, k = kb*32+q*8+e.
  short8 Bf[32];
  if (isL0) {
#pragma unroll
    for (int kb = 0; kb < 24; ++kb) {
      int k = kb * 32 + q * 8;
      const float* src = (k < INP) ? (w_ih0 + (size_t)j * INP + k)
                                   : (w_hh0 + (size_t)j * HH + (k - INP));
      Bf[kb] = load_cvt8(src);
    }
  } else {
#pragma unroll
    for (int kb = 0; kb < 32; ++kb) {
      int k = kb * 32 + q * 8;
      const float* src = (k < HH) ? (w_ih1 + (size_t)j * HH + k)
                                  : (w_hh1 + (size_t)j * HH + (k - HH));
      Bf[kb] = load_cvt8(src);
    }
  }
  const float bias = isL0 ? (b_ih0[j] + b_hh0[j]) : (b_ih1[j] + b_hh1[j]);

  // x bf16 fragments for current tick (L0 only)
  short8 xa[8];
  if (isL0) {
    const float* xp = x + ((size_t)(bg + ln) * TT + 0) * INP;
#pragma unroll
    for (int kb = 0; kb < 8; ++kb)
      xa[kb] = pack8(ntload4(xp + kb * 32 + q * 8), ntload4(xp + kb * 32 + q * 8 + 4));
  }

  gbar(cnt, 16 * ++phase);

  const f32x4 z = {0.f, 0.f, 0.f, 0.f};

  // ---- tick loop: at tick t, L0 computes h0(t) (t<T); L1 computes h1(t-1) (t>=1)
  for (int t = 0; t <= TT; ++t) {
    if (isL0) {
      if (t < TT) {
        // 1) issue next tick's x loads FIRST (fp32, nontemporal) - overlaps MFMA
        f32x4 xs[16];
        if (t + 1 < TT) {
          const float* xp = x + ((size_t)(bg + ln) * TT + (t + 1)) * INP;
#pragma unroll
          for (int kb = 0; kb < 8; ++kb) {
            xs[2 * kb]     = ntload4(xp + kb * 32 + q * 8);
            xs[2 * kb + 1] = ntload4(xp + kb * 32 + q * 8 + 4);
          }
        }
        // 2) MFMA for tick t
        const unsigned short* hp = hsl(h0f, (t + 1) & 1, g);  // h0(t-1)
        f32x4 ac[4] = {z, z, z, z};
#pragma unroll
        for (int kb = 0; kb < 8; ++kb)
          ac[kb & 3] = __builtin_amdgcn_mfma_f32_16x16x32_bf16(
              xa[kb], Bf[kb], ac[kb & 3], 0, 0, 0);
#pragma unroll
        for (int kb = 8; kb < 24; ++kb) {
          short8 Af = *(const short8*)(hp + ((size_t)(kb - 8) * 64 + lane) * 8);
          ac[kb & 3] = __builtin_amdgcn_mfma_f32_16x16x32_bf16(
              Af, Bf[kb], ac[kb & 3], 0, 0, 0);
        }
        f32x4 d;
        d[0] = ac[0][0] + ac[1][0] + ac[2][0] + ac[3][0];
        d[1] = ac[0][1] + ac[1][1] + ac[2][1] + ac[3][1];
        d[2] = ac[0][2] + ac[1][2] + ac[2][2] + ac[3][2];
        d[3] = ac[0][3] + ac[1][3] + ac[2][3] + ac[3][3];
        // 3) tanh -> LDS transpose stage
#pragma unroll
        for (int r = 0; r < 4; ++r) {
          float v = tanhf(d[r] + bias);
          hstage[((jrel >> 5) * 64 + ((jrel >> 3) & 3) * 16 + q * 4 + r) * 8 + (jrel & 7)]
              = bf16_rne(v);
        }
        // 4) convert staged x while LDS writes land
        if (t + 1 < TT) {
#pragma unroll
          for (int kb = 0; kb < 8; ++kb)
            xa[kb] = pack8(xs[2 * kb], xs[2 * kb + 1]);
        }
        __syncthreads();
        // 5) coalesced 2KB copy LDS -> group h0 buffer
        {
          unsigned short* wdst = hsl(h0f, t & 1, g) + (size_t)(role & 7) * 1024;
          *(uint2*)(wdst + tid * 4) = ((const uint2*)hstage)[tid];
        }
      }
    } else {
      if (t >= 1) {
        const unsigned short* hp0 = hsl(h0f, (t + 1) & 1, g);  // h0(t-1)
        const unsigned short* hp1 = hsl(h1f, t & 1, g);        // h1(t-2)
        f32x4 ac[4] = {z, z, z, z};
#pragma unroll
        for (int kb = 0; kb < 16; ++kb) {
          short8 Af = *(const short8*)(hp0 + ((size_t)kb * 64 + lane) * 8);
          ac[kb & 3] = __builtin_amdgcn_mfma_f32_16x16x32_bf16(
              Af, Bf[kb], ac[kb & 3], 0, 0, 0);
        }
#pragma unroll
        for (int kb = 16; kb < 32; ++kb) {
          short8 Af = *(const short8*)(hp1 + ((size_t)(kb - 16) * 64 + lane) * 8);
          ac[kb & 3] = __builtin_amdgcn_mfma_f32_16x16x32_bf16(
              Af, Bf[kb], ac[kb & 3], 0, 0, 0);
        }
        f32x4 d;
        d[0] = ac[0][0] + ac[1][0] + ac[2][0] + ac[3][0];
        d[1] = ac[0][1] + ac[1][1] + ac[2][1] + ac[3][1];
        d[2] = ac[0][2] + ac[1][2] + ac[2][2] + ac[3][2];
        d[3] = ac[0][3] + ac[1][3] + ac[2][3] + ac[3][3];
#pragma unroll
        for (int r = 0; r < 4; ++r) {
          float v = tanhf(d[r] + bias);
          hstage[((jrel >> 5) * 64 + ((jrel >> 3) & 3) * 16 + q * 4 + r) * 8 + (jrel & 7)]
              = bf16_rne(v);
        }
        __syncthreads();
        {
          unsigned short* wdst = hsl(h1f, (t + 1) & 1, g) + (size_t)(role & 7) * 1024;
          *(uint2*)(wdst + tid * 4) = ((const uint2*)hstage)[tid];
        }
      }
    }
    gbar(cnt, 16 * ++phase);
  }

  // ---- FC epilogue: out = h1(T-1) @ fc_w^T + fc_b. h1(T-1) is in h1f buf 1.
  if (wv == 0) {
    const unsigned short* hp = hsl(h1f, 1, g);
    const int o = role * 16 + ln;
    f32x4 ac[4] = {z, z, z, z};
#pragma unroll
    for (int kb = 0; kb < 16; ++kb) {
      int k = kb * 32 + q * 8;
      short8 Bfc = load_cvt8(fc_w + (size_t)o * HH + k);
      short8 Af  = *(const short8*)(hp + ((size_t)kb * 64 + lane) * 8);
      ac[kb & 3] = __builtin_amdgcn_mfma_f32_16x16x32_bf16(
          Af, Bfc, ac[kb & 3], 0, 0, 0);
    }
    const float fb = fc_b[o];
#pragma unroll
    for (int r = 0; r < 4; ++r) {
      float v = ac[0][r] + ac[1][r] + ac[2][r] + ac[3][r] + fb;
      out[(size_t)(bg + q * 4 + r) * OUTD + o] = v;
    }
  }
}

extern "C" void kernel_launch(void* const* d_in, const int* in_sizes, int n_in,
                              void* d_out, int out_size, void* d_ws, size_t ws_size,
                              hipStream_t stream) {
  (void)in_sizes; (void)n_in; (void)out_size; (void)ws_size;

  const float* x      = (const float*)d_in[0];
  const float* h0init = (const float*)d_in[1];
  const float* w_ih0  = (const float*)d_in[2];
  const float* w_hh0  = (const float*)d_in[3];
  const float* b_ih0  = (const float*)d_in[4];
  const float* b_hh0  = (const float*)d_in[5];
  const float* w_ih1  = (const float*)d_in[6];
  const float* w_hh1  = (const float*)d_in[7];
  const float* b_ih1  = (const float*)d_in[8];
  const float* b_hh1  = (const float*)d_in[9];
  const float* fc_w   = (const float*)d_in[10];
  const float* fc_b   = (const float*)d_in[11];
  float* out = (float*)d_out;

  // ws: [0,4096) barrier counters; h0 frag dbuf 256KB; h1 frag dbuf 256KB
  unsigned* bar = (unsigned*)d_ws;
  unsigned short* h0f = (unsigned short*)((char*)d_ws + 4096);
  unsigned short* h1f = h0f + 2 * NG * (16 * 64 * 8);

  hipMemsetAsync(d_ws, 0, 4096, stream);

  rnn_mfma<<<dim3(NBLK), dim3(256), 0, stream>>>(
      x, h0init, w_ih0, w_hh0, b_ih0, b_hh0, w_ih1, w_hh1, b_ih1, b_hh1,
      fc_w, fc_b, out, bar, h0f, h1f);
}

// Round 4
// 7366.161 us; speedup vs baseline: 1.1507x; 1.1507x over previous
//
#include <hip/hip_runtime.h>

#define BB   128   // batch
#define TT   1024  // time steps
#define INP  256   // input dim
#define HH   512   // hidden dim
#define OUTD 256   // output dim
#define GB   16    // batches per group
#define NG   8     // groups (one per XCD via blockIdx%8)
#define NBLK 64    // 8 groups x 8 combined-role j-slice blocks

typedef float  f32x4  __attribute__((ext_vector_type(4)));
typedef short  short8 __attribute__((ext_vector_type(8)));

__device__ __forceinline__ unsigned short bf16_rne(float f) {
  union { float f; unsigned u; } v; v.f = f;
  unsigned r = v.u + 0x7fffu + ((v.u >> 16) & 1u);
  return (unsigned short)(r >> 16);
}

__device__ __forceinline__ short8 pack8(f32x4 a, f32x4 b) {
  union { unsigned short s[8]; short8 v; } u;
  u.s[0] = bf16_rne(a[0]); u.s[1] = bf16_rne(a[1]);
  u.s[2] = bf16_rne(a[2]); u.s[3] = bf16_rne(a[3]);
  u.s[4] = bf16_rne(b[0]); u.s[5] = bf16_rne(b[1]);
  u.s[6] = bf16_rne(b[2]); u.s[7] = bf16_rne(b[3]);
  return u.v;
}

__device__ __forceinline__ short8 load_cvt8(const float* p) {
  const f32x4* q = (const f32x4*)p;
  return pack8(q[0], q[1]);
}

__device__ __forceinline__ f32x4 ntload4(const float* p) {
  return __builtin_nontemporal_load((const f32x4*)p);
}

// Monotonic-counter group barrier (8 blocks/group). Relaxed polling + one
// acquire at exit. __syncthreads at entry drains vmem (stores visible in
// L2/L3 before thread 0's release-add). Protocol validated R1-R3.
__device__ __forceinline__ void gbar(unsigned* cnt, unsigned target) {
  __syncthreads();
  if (threadIdx.x == 0) {
    __hip_atomic_fetch_add(cnt, 1u, __ATOMIC_RELEASE, __HIP_MEMORY_SCOPE_AGENT);
    while (__hip_atomic_load(cnt, __ATOMIC_RELAXED, __HIP_MEMORY_SCOPE_AGENT) < target)
      __builtin_amdgcn_s_sleep(1);
    (void)__hip_atomic_load(cnt, __ATOMIC_ACQUIRE, __HIP_MEMORY_SCOPE_AGENT);
  }
  __syncthreads();
}

// h-state fragment slots: per (slot, group): [kb(16)][lane(64)][e(8)] bf16 = 16KB.
// Value (b_local, j): kb = j>>5, lane' = ((j>>3)&3)*16 + b_local, e = j&7.
// h0 ring: 2 slots. h1 ring: 4 slots (consumer lags 2 ticks; 2 slots would let
// a fast peer overwrite what a slow peer is still reading).
__device__ __forceinline__ unsigned short* hslot(unsigned short* base, int slot, int g) {
  return base + ((size_t)(slot * NG + g)) * (16 * 64 * 8);
}

__global__ void __launch_bounds__(256, 1) rnn_mfma(
    const float* __restrict__ x,       // [B][T][IN]
    const float* __restrict__ h0init,  // [2][B][H]
    const float* __restrict__ w_ih0,   // [H][IN]
    const float* __restrict__ w_hh0,   // [H][H]
    const float* __restrict__ b_ih0,   // [H]
    const float* __restrict__ b_hh0,   // [H]
    const float* __restrict__ w_ih1,   // [H][H]
    const float* __restrict__ w_hh1,   // [H][H]
    const float* __restrict__ b_ih1,   // [H]
    const float* __restrict__ b_hh1,   // [H]
    const float* __restrict__ fc_w,    // [OUT][H]
    const float* __restrict__ fc_b,    // [OUT]
    float* __restrict__ out,           // [B][OUT]
    unsigned* __restrict__ bar,        // NG counters, 64B apart
    unsigned short* __restrict__ h0f,  // h0 ring: 2 slots x NG x 16KB
    unsigned short* __restrict__ h1f)  // h1 ring: 4 slots x NG x 16KB
{
  const int g    = blockIdx.x & 7;       // group -> XCD locality
  const int jb   = blockIdx.x >> 3;      // j-slice 0..7 (both layers)
  const int tid  = threadIdx.x;
  const int wv   = tid >> 6;
  const int lane = tid & 63;
  const int ln   = lane & 15;            // A-row (batch) / B-col (j)
  const int q    = lane >> 4;            // quad
  const int j0   = jb * 64 + wv * 16 + ln;  // output column (both layers)
  const int bg   = g * GB;
  unsigned* cnt  = bar + g * 16;
  unsigned phase = 0;

  // ---- init: h0init -> h0 slot 1, h1init -> h1 slot 3 (redundant across the
  // group's 8 blocks; identical values, benign).
  for (int c = tid; c < 2048; c += 256) {
    int a  = c >> 10;            // 0 -> h0, 1 -> h1
    int bl = (c >> 6) & 15;
    int j8 = (c & 63) * 8;
    short8 v = load_cvt8(h0init + ((size_t)a * BB + (bg + bl)) * HH + j8);
    unsigned short* dst = hslot(a ? h1f : h0f, a ? 3 : 1, g)
        + ((size_t)((j8 >> 5) * 64 + ((j8 >> 3) & 3) * 16 + bl)) * 8;
    *(short8*)dst = v;
  }

  // ---- weight B-fragments -> registers (once). Lane: row j0, k = kb*32+q*8+e.
  short8 Bf0[24];  // L0: w_ih0 (kb 0..7, K=256) then w_hh0 (kb 8..23, K=512)
  short8 Bf1[32];  // L1: w_ih1 (kb 0..15) then w_hh1 (kb 16..31)
#pragma unroll
  for (int kb = 0; kb < 24; ++kb) {
    int k = kb * 32 + q * 8;
    const float* src = (k < INP) ? (w_ih0 + (size_t)j0 * INP + k)
                                 : (w_hh0 + (size_t)j0 * HH + (k - INP));
    Bf0[kb] = load_cvt8(src);
  }
#pragma unroll
  for (int kb = 0; kb < 32; ++kb) {
    int k = kb * 32 + q * 8;
    const float* src = (k < HH) ? (w_ih1 + (size_t)j0 * HH + k)
                                : (w_hh1 + (size_t)j0 * HH + (k - HH));
    Bf1[kb] = load_cvt8(src);
  }
  const float bias0 = b_ih0[j0] + b_hh0[j0];
  const float bias1 = b_ih1[j0] + b_hh1[j0];

  // raw fp32 x for tick 0 (packed at tick top; held across barrier)
  f32x4 xraw[16];
  {
    const float* xp = x + ((size_t)(bg + ln) * TT + 0) * INP;
#pragma unroll
    for (int kb = 0; kb < 8; ++kb) {
      xraw[2 * kb]     = ntload4(xp + kb * 32 + q * 8);
      xraw[2 * kb + 1] = ntload4(xp + kb * 32 + q * 8 + 4);
    }
  }

  gbar(cnt, 8 * ++phase);

  const f32x4 z = {0.f, 0.f, 0.f, 0.f};
  short8 xa[8];

  // ---- tick loop: tick t computes h0(t) (t<TT) and h1(t-1) (t>=1);
  // one barrier per tick.
#pragma unroll 1
  for (int t = 0; t <= TT; ++t) {
    const bool doL0 = (t < TT);
    const bool doL1 = (t >= 1);

    // pack x(t) from raw regs loaded last tick (data long since arrived)
    if (doL0) {
#pragma unroll
      for (int kb = 0; kb < 8; ++kb)
        xa[kb] = pack8(xraw[2 * kb], xraw[2 * kb + 1]);
    }

    // issue shared h0(t-1) A-frag loads (slot (t-1)&1 == (t+1)&1)
    const unsigned short* hp0 = hslot(h0f, (t + 1) & 1, g);
    short8 Af0[16];
#pragma unroll
    for (int kb = 0; kb < 16; ++kb)
      Af0[kb] = *(const short8*)(hp0 + ((size_t)kb * 64 + lane) * 8);

    // issue h1(t-2) A-frag loads (slot (t-2)&3 == (t+2)&3)
    short8 Af1[16];
    if (doL1) {
      const unsigned short* hp1 = hslot(h1f, (t + 2) & 3, g);
#pragma unroll
      for (int kb = 0; kb < 16; ++kb)
        Af1[kb] = *(const short8*)(hp1 + ((size_t)kb * 64 + lane) * 8);
    }

    // ---- MFMAs
    f32x4 ac0[4] = {z, z, z, z};
    f32x4 ac1[4] = {z, z, z, z};
    if (doL0) {
#pragma unroll
      for (int kb = 0; kb < 8; ++kb)
        ac0[kb & 3] = __builtin_amdgcn_mfma_f32_16x16x32_bf16(
            xa[kb], Bf0[kb], ac0[kb & 3], 0, 0, 0);
#pragma unroll
      for (int kb = 8; kb < 24; ++kb)
        ac0[kb & 3] = __builtin_amdgcn_mfma_f32_16x16x32_bf16(
            Af0[kb - 8], Bf0[kb], ac0[kb & 3], 0, 0, 0);
    }
    if (doL1) {
#pragma unroll
      for (int kb = 0; kb < 16; ++kb)
        ac1[kb & 3] = __builtin_amdgcn_mfma_f32_16x16x32_bf16(
            Af0[kb], Bf1[kb], ac1[kb & 3], 0, 0, 0);
#pragma unroll
      for (int kb = 16; kb < 32; ++kb)
        ac1[kb & 3] = __builtin_amdgcn_mfma_f32_16x16x32_bf16(
            Af1[kb - 16], Bf1[kb], ac1[kb & 3], 0, 0, 0);
    }

    // issue next tick's x loads (queued AFTER the h loads -> h never waits on x;
    // ~2.5K cycles of slack before the pack at next tick's top)
    if (t + 1 < TT) {
      const float* xp = x + ((size_t)(bg + ln) * TT + (t + 1)) * INP;
#pragma unroll
      for (int kb = 0; kb < 8; ++kb) {
        xraw[2 * kb]     = ntload4(xp + kb * 32 + q * 8);
        xraw[2 * kb + 1] = ntload4(xp + kb * 32 + q * 8 + 4);
      }
    }

    // ---- tanh + scatter stores (2B x4 per lane, R2-validated pattern)
    if (doL0) {
      f32x4 d;
      d[0] = ac0[0][0] + ac0[1][0] + ac0[2][0] + ac0[3][0];
      d[1] = ac0[0][1] + ac0[1][1] + ac0[2][1] + ac0[3][1];
      d[2] = ac0[0][2] + ac0[1][2] + ac0[2][2] + ac0[3][2];
      d[3] = ac0[0][3] + ac0[1][3] + ac0[2][3] + ac0[3][3];
      unsigned short* wdst = hslot(h0f, t & 1, g);
#pragma unroll
      for (int r = 0; r < 4; ++r) {
        float v = tanhf(d[r] + bias0);
        wdst[((size_t)((j0 >> 5) * 64 + ((j0 >> 3) & 3) * 16 + q * 4 + r)) * 8 + (j0 & 7)]
            = bf16_rne(v);
      }
    }
    if (doL1) {
      f32x4 d;
      d[0] = ac1[0][0] + ac1[1][0] + ac1[2][0] + ac1[3][0];
      d[1] = ac1[0][1] + ac1[1][1] + ac1[2][1] + ac1[3][1];
      d[2] = ac1[0][2] + ac1[1][2] + ac1[2][2] + ac1[3][2];
      d[3] = ac1[0][3] + ac1[1][3] + ac1[2][3] + ac1[3][3];
      unsigned short* wdst = hslot(h1f, (t + 3) & 3, g);  // slot (t-1)&3
#pragma unroll
      for (int r = 0; r < 4; ++r) {
        float v = tanhf(d[r] + bias1);
        wdst[((size_t)((j0 >> 5) * 64 + ((j0 >> 3) & 3) * 16 + q * 4 + r)) * 8 + (j0 & 7)]
            = bf16_rne(v);
      }
    }

    gbar(cnt, 8 * ++phase);
  }

  // ---- FC epilogue: out = h1(TT-1) @ fc_w^T + fc_b. h1(TT-1) in slot (TT-1)&3 = 3.
  // Waves 0,1 of each block: o-tile = jb*2 + wv.
  if (wv < 2) {
    const unsigned short* hp = hslot(h1f, 3, g);
    const int o = (jb * 2 + wv) * 16 + ln;
    f32x4 ac[4] = {z, z, z, z};
#pragma unroll
    for (int kb = 0; kb < 16; ++kb) {
      int k = kb * 32 + q * 8;
      short8 Bfc = load_cvt8(fc_w + (size_t)o * HH + k);
      short8 Af  = *(const short8*)(hp + ((size_t)kb * 64 + lane) * 8);
      ac[kb & 3] = __builtin_amdgcn_mfma_f32_16x16x32_bf16(
          Af, Bfc, ac[kb & 3], 0, 0, 0);
    }
    const float fb = fc_b[o];
#pragma unroll
    for (int r = 0; r < 4; ++r) {
      float v = ac[0][r] + ac[1][r] + ac[2][r] + ac[3][r] + fb;
      out[(size_t)(bg + q * 4 + r) * OUTD + o] = v;
    }
  }
}

extern "C" void kernel_launch(void* const* d_in, const int* in_sizes, int n_in,
                              void* d_out, int out_size, void* d_ws, size_t ws_size,
                              hipStream_t stream) {
  (void)in_sizes; (void)n_in; (void)out_size; (void)ws_size;

  const float* x      = (const float*)d_in[0];
  const float* h0init = (const float*)d_in[1];
  const float* w_ih0  = (const float*)d_in[2];
  const float* w_hh0  = (const float*)d_in[3];
  const float* b_ih0  = (const float*)d_in[4];
  const float* b_hh0  = (const float*)d_in[5];
  const float* w_ih1  = (const float*)d_in[6];
  const float* w_hh1  = (const float*)d_in[7];
  const float* b_ih1  = (const float*)d_in[8];
  const float* b_hh1  = (const float*)d_in[9];
  const float* fc_w   = (const float*)d_in[10];
  const float* fc_b   = (const float*)d_in[11];
  float* out = (float*)d_out;

  // ws: [0,4096) barrier counters; h0 ring 2x8x16KB=256KB; h1 ring 4x8x16KB=512KB
  unsigned* bar = (unsigned*)d_ws;
  unsigned short* h0f = (unsigned short*)((char*)d_ws + 4096);
  unsigned short* h1f = h0f + 2 * NG * (16 * 64 * 8);

  hipMemsetAsync(d_ws, 0, 4096, stream);

  rnn_mfma<<<dim3(NBLK), dim3(256), 0, stream>>>(
      x, h0init, w_ih0, w_hh0, b_ih0, b_hh0, w_ih1, w_hh1, b_ih1, b_hh1,
      fc_w, fc_b, out, bar, h0f, h1f);
}

// Round 5
// 5477.209 us; speedup vs baseline: 1.5476x; 1.3449x over previous
//
#include <hip/hip_runtime.h>

#define BB   128   // batch
#define TT   1024  // time steps
#define INP  256   // input dim
#define HH   512   // hidden dim
#define OUTD 256   // output dim
#define GB   16    // batches per group
#define NG   8     // groups
#define NBLK 128   // 8 groups x (8 L0 + 8 L1 j-slice blocks)

typedef float  f32x4  __attribute__((ext_vector_type(4)));
typedef short  short8 __attribute__((ext_vector_type(8)));
typedef unsigned long long u64;

__device__ __forceinline__ unsigned short bf16_rne(float f) {
  union { float f; unsigned u; } v; v.f = f;
  unsigned r = v.u + 0x7fffu + ((v.u >> 16) & 1u);
  return (unsigned short)(r >> 16);
}

__device__ __forceinline__ short8 pack8(f32x4 a, f32x4 b) {
  union { unsigned short s[8]; short8 v; } u;
  u.s[0] = bf16_rne(a[0]); u.s[1] = bf16_rne(a[1]);
  u.s[2] = bf16_rne(a[2]); u.s[3] = bf16_rne(a[3]);
  u.s[4] = bf16_rne(b[0]); u.s[5] = bf16_rne(b[1]);
  u.s[6] = bf16_rne(b[2]); u.s[7] = bf16_rne(b[3]);
  return u.v;
}

__device__ __forceinline__ short8 load_cvt8(const float* p) {
  const f32x4* q = (const f32x4*)p;
  return pack8(q[0], q[1]);
}

__device__ __forceinline__ f32x4 ntload4(const float* p) {
  return __builtin_nontemporal_load((const f32x4*)p);
}

// ---- point-of-coherence h-state access (sc0+sc1: bypass L1/L2, hit MALL).
// No cache-wide fences anywhere in the kernel; coherence is per-access.
__device__ __forceinline__ short8 sysload8(const unsigned short* p) {
  union { u64 q[2]; short8 v; } u;
  const u64* pp = (const u64*)p;
  u.q[0] = __hip_atomic_load(pp,     __ATOMIC_RELAXED, __HIP_MEMORY_SCOPE_SYSTEM);
  u.q[1] = __hip_atomic_load(pp + 1, __ATOMIC_RELAXED, __HIP_MEMORY_SCOPE_SYSTEM);
  return u.v;
}
__device__ __forceinline__ void sysstore8(unsigned short* p, short8 v) {
  union { short8 v; u64 q[2]; } u; u.v = v;
  u64* pp = (u64*)p;
  __hip_atomic_store(pp,     u.q[0], __ATOMIC_RELAXED, __HIP_MEMORY_SCOPE_SYSTEM);
  __hip_atomic_store(pp + 1, u.q[1], __ATOMIC_RELAXED, __HIP_MEMORY_SCOPE_SYSTEM);
}
__device__ __forceinline__ void sysstore2(unsigned short* p, unsigned short v) {
  __hip_atomic_store(p, v, __ATOMIC_RELAXED, __HIP_MEMORY_SCOPE_SYSTEM);
}

// Relaxed-only group barrier (16 blocks/group). __syncthreads at entry drains
// vmcnt for every wave (sc1 stores ack from the coherence point), so all h
// stores are MALL-visible before thread 0's add. No acquire fence: consumers
// read h ONLY via sc1 loads, so nothing stale is ever observed.
__device__ __forceinline__ void gbar(unsigned* cnt, unsigned target) {
  __syncthreads();
  if (threadIdx.x == 0) {
    __hip_atomic_fetch_add(cnt, 1u, __ATOMIC_RELAXED, __HIP_MEMORY_SCOPE_AGENT);
    while (__hip_atomic_load(cnt, __ATOMIC_RELAXED, __HIP_MEMORY_SCOPE_AGENT) < target)
      __builtin_amdgcn_s_sleep(1);
  }
  __syncthreads();
}

// h-state fragment slots: per (slot, group): [kb(16)][lane(64)][e(8)] bf16 = 16KB.
// Value (b_local, j): kb = j>>5, lane' = ((j>>3)&3)*16 + b_local, e = j&7.
// 4-slot rings: max concurrent writer/reader tick distance is 2 (< 4).
__device__ __forceinline__ unsigned short* hslot(unsigned short* base, int slot, int g) {
  return base + ((size_t)(slot * NG + g)) * (16 * 64 * 8);
}

__global__ void __launch_bounds__(256, 1) rnn_mfma(
    const float* __restrict__ x,       // [B][T][IN]
    const float* __restrict__ h0init,  // [2][B][H]
    const float* __restrict__ w_ih0,   // [H][IN]
    const float* __restrict__ w_hh0,   // [H][H]
    const float* __restrict__ b_ih0,   // [H]
    const float* __restrict__ b_hh0,   // [H]
    const float* __restrict__ w_ih1,   // [H][H]
    const float* __restrict__ w_hh1,   // [H][H]
    const float* __restrict__ b_ih1,   // [H]
    const float* __restrict__ b_hh1,   // [H]
    const float* __restrict__ fc_w,    // [OUT][H]
    const float* __restrict__ fc_b,    // [OUT]
    float* __restrict__ out,           // [B][OUT]
    unsigned* __restrict__ bar,        // NG counters, 64B apart
    unsigned short* __restrict__ h0f,  // h0 ring: 4 slots x NG x 16KB
    unsigned short* __restrict__ h1f)  // h1 ring: 4 slots x NG x 16KB
{
  const int g    = blockIdx.x & 7;
  const int role = blockIdx.x >> 3;      // 0..7: L0 j-slices; 8..15: L1 j-slices
  const bool isL0 = role < 8;
  const int tid  = threadIdx.x;
  const int wv   = tid >> 6;
  const int lane = tid & 63;
  const int ln   = lane & 15;            // A-row (batch) / B-col (j)
  const int q    = lane >> 4;            // quad
  const int j0   = (role & 7) * 64 + wv * 16 + ln;  // output column
  const int bg   = g * GB;
  unsigned* cnt  = bar + g * 16;
  unsigned phase = 0;

  // ---- init: h0init -> h0 slot 3, h1init -> h1 slot 3 (read at t=0 / t=1).
  // Redundant across the group's 16 blocks; identical values, benign.
  for (int c = tid; c < 2048; c += 256) {
    int a  = c >> 10;            // 0 -> h0, 1 -> h1
    int bl = (c >> 6) & 15;
    int j8 = (c & 63) * 8;
    short8 v = load_cvt8(h0init + ((size_t)a * BB + (bg + bl)) * HH + j8);
    unsigned short* dst = hslot(a ? h1f : h0f, 3, g)
        + ((size_t)((j8 >> 5) * 64 + ((j8 >> 3) & 3) * 16 + bl)) * 8;
    sysstore8(dst, v);
  }

  // ---- weight B-fragments -> registers (once). Lane: row j0, k = kb*32+q*8+e.
  short8 Bf0[24];  // L0 only: w_ih0 (kb 0..7) then w_hh0 (kb 8..23)
  short8 Bf1[32];  // L1 only: w_ih1 (kb 0..15) then w_hh1 (kb 16..31)
  if (isL0) {
#pragma unroll
    for (int kb = 0; kb < 24; ++kb) {
      int k = kb * 32 + q * 8;
      const float* src = (k < INP) ? (w_ih0 + (size_t)j0 * INP + k)
                                   : (w_hh0 + (size_t)j0 * HH + (k - INP));
      Bf0[kb] = load_cvt8(src);
    }
  } else {
#pragma unroll
    for (int kb = 0; kb < 32; ++kb) {
      int k = kb * 32 + q * 8;
      const float* src = (k < HH) ? (w_ih1 + (size_t)j0 * HH + k)
                                  : (w_hh1 + (size_t)j0 * HH + (k - HH));
      Bf1[kb] = load_cvt8(src);
    }
  }
  const float bias = isL0 ? (b_ih0[j0] + b_hh0[j0]) : (b_ih1[j0] + b_hh1[j0]);

  // x(0) bf16 fragments (L0 only)
  short8 xa[8];
  if (isL0) {
    const float* xp = x + ((size_t)(bg + ln) * TT + 0) * INP;
#pragma unroll
    for (int kb = 0; kb < 8; ++kb)
      xa[kb] = pack8(ntload4(xp + kb * 32 + q * 8), ntload4(xp + kb * 32 + q * 8 + 4));
  }

  gbar(cnt, 16 * ++phase);

  const f32x4 z = {0.f, 0.f, 0.f, 0.f};

  // ---- tick loop: tick t: L0 computes h0(t) (t<TT); L1 computes h1(t-1) (t>=1).
  // One barrier per tick. h0(t-1) lives in slot (t+3)&3; h1(t-2) in (t+2)&3.
#pragma unroll 1
  for (int t = 0; t <= TT; ++t) {
    if (isL0) {
      if (t < TT) {
        const unsigned short* hp0 = hslot(h0f, (t + 3) & 3, g);  // h0(t-1)
        short8 Af[16];
#pragma unroll
        for (int kb = 0; kb < 16; ++kb)
          Af[kb] = sysload8(hp0 + ((size_t)kb * 64 + lane) * 8);

        f32x4 ac[4] = {z, z, z, z};
#pragma unroll
        for (int kb = 0; kb < 8; ++kb)
          ac[kb & 3] = __builtin_amdgcn_mfma_f32_16x16x32_bf16(
              xa[kb], Bf0[kb], ac[kb & 3], 0, 0, 0);
#pragma unroll
        for (int kb = 8; kb < 24; ++kb)
          ac[kb & 3] = __builtin_amdgcn_mfma_f32_16x16x32_bf16(
              Af[kb - 8], Bf0[kb], ac[kb & 3], 0, 0, 0);

        f32x4 d;
        d[0] = ac[0][0] + ac[1][0] + ac[2][0] + ac[3][0];
        d[1] = ac[0][1] + ac[1][1] + ac[2][1] + ac[3][1];
        d[2] = ac[0][2] + ac[1][2] + ac[2][2] + ac[3][2];
        d[3] = ac[0][3] + ac[1][3] + ac[2][3] + ac[3][3];
        unsigned short* wdst = hslot(h0f, t & 3, g);
#pragma unroll
        for (int r = 0; r < 4; ++r) {
          float v = tanhf(d[r] + bias);
          sysstore2(wdst + ((size_t)((j0 >> 5) * 64 + ((j0 >> 3) & 3) * 16 + q * 4 + r)) * 8
                        + (j0 & 7), bf16_rne(v));
        }
        // next tick's x: NT loads issued at tail; barrier's vmcnt(0) drain
        // covers their completion, so the pack costs no extra stall.
        if (t + 1 < TT) {
          const float* xp = x + ((size_t)(bg + ln) * TT + (t + 1)) * INP;
          f32x4 xr[16];
#pragma unroll
          for (int kb = 0; kb < 8; ++kb) {
            xr[2 * kb]     = ntload4(xp + kb * 32 + q * 8);
            xr[2 * kb + 1] = ntload4(xp + kb * 32 + q * 8 + 4);
          }
#pragma unroll
          for (int kb = 0; kb < 8; ++kb)
            xa[kb] = pack8(xr[2 * kb], xr[2 * kb + 1]);
        }
      }
    } else {
      if (t >= 1) {
        const unsigned short* hp0 = hslot(h0f, (t + 3) & 3, g);  // h0(t-1)
        const unsigned short* hp1 = hslot(h1f, (t + 2) & 3, g);  // h1(t-2)
        f32x4 ac[4] = {z, z, z, z};
        // phase 1: h0(t-1) x w_ih1 (16-frag A window, then reused)
        {
          short8 Af[16];
#pragma unroll
          for (int kb = 0; kb < 16; ++kb)
            Af[kb] = sysload8(hp0 + ((size_t)kb * 64 + lane) * 8);
#pragma unroll
          for (int kb = 0; kb < 16; ++kb)
            ac[kb & 3] = __builtin_amdgcn_mfma_f32_16x16x32_bf16(
                Af[kb], Bf1[kb], ac[kb & 3], 0, 0, 0);
        }
        // phase 2: h1(t-2) x w_hh1
        {
          short8 Af[16];
#pragma unroll
          for (int kb = 0; kb < 16; ++kb)
            Af[kb] = sysload8(hp1 + ((size_t)kb * 64 + lane) * 8);
#pragma unroll
          for (int kb = 0; kb < 16; ++kb)
            ac[kb & 3] = __builtin_amdgcn_mfma_f32_16x16x32_bf16(
                Af[kb], Bf1[kb + 16], ac[kb & 3], 0, 0, 0);
        }
        f32x4 d;
        d[0] = ac[0][0] + ac[1][0] + ac[2][0] + ac[3][0];
        d[1] = ac[0][1] + ac[1][1] + ac[2][1] + ac[3][1];
        d[2] = ac[0][2] + ac[1][2] + ac[2][2] + ac[3][2];
        d[3] = ac[0][3] + ac[1][3] + ac[2][3] + ac[3][3];
        unsigned short* wdst = hslot(h1f, (t + 3) & 3, g);  // h1(t-1)
#pragma unroll
        for (int r = 0; r < 4; ++r) {
          float v = tanhf(d[r] + bias);
          sysstore2(wdst + ((size_t)((j0 >> 5) * 64 + ((j0 >> 3) & 3) * 16 + q * 4 + r)) * 8
                        + (j0 & 7), bf16_rne(v));
        }
      }
    }
    gbar(cnt, 16 * ++phase);
  }

  // ---- FC epilogue: out = h1(TT-1) @ fc_w^T + fc_b. h1(1023) in slot 3.
  // 16 roles x wave 0: o-tile = role.
  if (wv == 0) {
    const unsigned short* hp = hslot(h1f, 3, g);
    const int o = role * 16 + ln;
    f32x4 ac[4] = {z, z, z, z};
#pragma unroll
    for (int kb = 0; kb < 16; ++kb) {
      int k = kb * 32 + q * 8;
      short8 Bfc = load_cvt8(fc_w + (size_t)o * HH + k);
      short8 Af  = sysload8(hp + ((size_t)kb * 64 + lane) * 8);
      ac[kb & 3] = __builtin_amdgcn_mfma_f32_16x16x32_bf16(
          Af, Bfc, ac[kb & 3], 0, 0, 0);
    }
    const float fb = fc_b[o];
#pragma unroll
    for (int r = 0; r < 4; ++r) {
      float v = ac[0][r] + ac[1][r] + ac[2][r] + ac[3][r] + fb;
      out[(size_t)(bg + q * 4 + r) * OUTD + o] = v;
    }
  }
}

extern "C" void kernel_launch(void* const* d_in, const int* in_sizes, int n_in,
                              void* d_out, int out_size, void* d_ws, size_t ws_size,
                              hipStream_t stream) {
  (void)in_sizes; (void)n_in; (void)out_size; (void)ws_size;

  const float* x      = (const float*)d_in[0];
  const float* h0init = (const float*)d_in[1];
  const float* w_ih0  = (const float*)d_in[2];
  const float* w_hh0  = (const float*)d_in[3];
  const float* b_ih0  = (const float*)d_in[4];
  const float* b_hh0  = (const float*)d_in[5];
  const float* w_ih1  = (const float*)d_in[6];
  const float* w_hh1  = (const float*)d_in[7];
  const float* b_ih1  = (const float*)d_in[8];
  const float* b_hh1  = (const float*)d_in[9];
  const float* fc_w   = (const float*)d_in[10];
  const float* fc_b   = (const float*)d_in[11];
  float* out = (float*)d_out;

  // ws: [0,4096) barrier counters; h0 ring 4x8x16KB=512KB; h1 ring 512KB
  unsigned* bar = (unsigned*)d_ws;
  unsigned short* h0f = (unsigned short*)((char*)d_ws + 4096);
  unsigned short* h1f = h0f + 4 * NG * (16 * 64 * 8);

  hipMemsetAsync(d_ws, 0, 4096, stream);

  rnn_mfma<<<dim3(NBLK), dim3(256), 0, stream>>>(
      x, h0init, w_ih0, w_hh0, b_ih0, b_hh0, w_ih1, w_hh1, b_ih1, b_hh1,
      fc_w, fc_b, out, bar, h0f, h1f);
}